// Round 1
// baseline (12681.835 us; speedup 1.0000x reference)
//
#include <hip/hip_runtime.h>
#include <math.h>

#define NN 50000
#define NE 800000
#define HID 128

// ---------------- LayerNorm over rows of 128 ----------------
__global__ __launch_bounds__(256) void ln_kernel(const float* __restrict__ h,
    const float* __restrict__ g, const float* __restrict__ b,
    float* __restrict__ o, int n)
{
  int r = blockIdx.x * 4 + (threadIdx.x >> 6);
  int lane = threadIdx.x & 63;
  if (r >= n) return;
  const float* hr = h + (size_t)r * HID;
  float v0 = hr[lane], v1 = hr[lane + 64];
  float s1 = v0 + v1, s2 = v0 * v0 + v1 * v1;
  #pragma unroll
  for (int m = 1; m < 64; m <<= 1) {
    s1 += __shfl_xor(s1, m, 64);
    s2 += __shfl_xor(s2, m, 64);
  }
  float mu = s1 * (1.0f / 128.0f);
  float var = s2 * (1.0f / 128.0f) - mu * mu;
  float rs = rsqrtf(var + 1e-5f);
  float* orow = o + (size_t)r * HID;
  orow[lane]      = (v0 - mu) * rs * g[lane]      + b[lane];
  orow[lane + 64] = (v1 - mu) * rs * g[lane + 64] + b[lane + 64];
}

__global__ __launch_bounds__(256) void zero4_kernel(float4* __restrict__ p, int n4)
{
  int i = blockIdx.x * 256 + threadIdx.x;
  if (i < n4) p[i] = make_float4(0.f, 0.f, 0.f, 0.f);
}

__device__ __forceinline__ float silu_f(float x) { return x / (1.0f + expf(-x)); }

// 64x128 output tile, 256 threads, 4x8 micro-tile per thread.
template<int KW>
__device__ __forceinline__ void gemm_chunk(const float (*As)[36], const float (*Bs)[128],
                                           int ty4, int tx8, float acc[4][8])
{
  #pragma unroll 8
  for (int kk = 0; kk < KW; ++kk) {
    float a[4];
    #pragma unroll
    for (int i = 0; i < 4; ++i) a[i] = As[ty4 + i][kk];
    const float4 u = *(const float4*)&Bs[kk][tx8];
    const float4 v = *(const float4*)&Bs[kk][tx8 + 4];
    const float bb[8] = {u.x, u.y, u.z, u.w, v.x, v.y, v.z, v.w};
    #pragma unroll
    for (int i = 0; i < 4; ++i)
      #pragma unroll
      for (int j = 0; j < 8; ++j)
        acc[i][j] = fmaf(a[i], bb[j], acc[i][j]);
  }
}

// C = [R +] act(ln?(concat(A0,A1) @ W^T + bias)); A* are [n,128], W is [128,KTOT].
template<int KTOT, bool DOLN, bool DOSILU, bool DORES>
__global__ __launch_bounds__(256) void node_gemm(
    const float* __restrict__ A0, const float* __restrict__ A1,
    const float* __restrict__ W, const float* __restrict__ bias,
    const float* __restrict__ lng, const float* __restrict__ lnb,
    const float* __restrict__ R, float* __restrict__ C, int n)
{
  __shared__ float As[64][36];
  __shared__ float Bs[32][128];
  const int tid = threadIdx.x;
  const int tx8 = (tid & 15) * 8;
  const int ty4 = (tid >> 4) * 4;
  const int n0 = blockIdx.x * 64;
  float acc[4][8] = {};

  for (int kc = 0; kc < KTOT / 32; ++kc) {
    const float* Asrc = (KTOT == 256 && kc >= 4) ? A1 : A0;
    const int k0 = (kc & 3) * 32;
    #pragma unroll
    for (int i = 0; i < 2; ++i) {
      int s = tid + i * 256;
      int e = s >> 3, f4 = (s & 7) * 4;
      int r = n0 + e;
      float4 v = make_float4(0.f, 0.f, 0.f, 0.f);
      if (r < n) v = *(const float4*)(Asrc + (size_t)r * HID + k0 + f4);
      *(float4*)&As[e][f4] = v;
    }
    {
      int m = tid >> 1, kks = (tid & 1) * 16;
      const float* wr = W + (size_t)m * KTOT + kc * 32 + kks;
      #pragma unroll
      for (int j = 0; j < 16; ++j) Bs[kks + j][m] = wr[j];
    }
    __syncthreads();
    gemm_chunk<32>(As, Bs, ty4, tx8, acc);
    __syncthreads();
  }

  float bv[8];
  #pragma unroll
  for (int j = 0; j < 8; ++j) bv[j] = bias[tx8 + j];
  #pragma unroll
  for (int i = 0; i < 4; ++i)
    #pragma unroll
    for (int j = 0; j < 8; ++j) acc[i][j] += bv[j];

  if (DOLN) {
    float gv[8], lv[8];
    #pragma unroll
    for (int j = 0; j < 8; ++j) { gv[j] = lng[tx8 + j]; lv[j] = lnb[tx8 + j]; }
    #pragma unroll
    for (int i = 0; i < 4; ++i) {
      float s1 = 0.f, s2 = 0.f;
      #pragma unroll
      for (int j = 0; j < 8; ++j) { s1 += acc[i][j]; s2 += acc[i][j] * acc[i][j]; }
      #pragma unroll
      for (int m = 1; m < 16; m <<= 1) { s1 += __shfl_xor(s1, m, 64); s2 += __shfl_xor(s2, m, 64); }
      float mu = s1 * (1.0f / 128.0f);
      float var = s2 * (1.0f / 128.0f) - mu * mu;
      float rs = rsqrtf(var + 1e-5f);
      #pragma unroll
      for (int j = 0; j < 8; ++j) acc[i][j] = (acc[i][j] - mu) * rs * gv[j] + lv[j];
    }
  }
  if (DOSILU) {
    #pragma unroll
    for (int i = 0; i < 4; ++i)
      #pragma unroll
      for (int j = 0; j < 8; ++j) acc[i][j] = silu_f(acc[i][j]);
  }
  #pragma unroll
  for (int i = 0; i < 4; ++i) {
    int r = n0 + ty4 + i;
    if (r < n) {
      float* cr = C + (size_t)r * HID + tx8;
      if (DORES) {
        const float* rr = R + (size_t)r * HID + tx8;
        #pragma unroll
        for (int j = 0; j < 8; ++j) cr[j] = rr[j] + acc[i][j];
      } else {
        #pragma unroll
        for (int j = 0; j < 8; ++j) cr[j] = acc[i][j];
      }
    }
  }
}

// Fused edge MLP: gather -> GEMM1(272) -> +b -> LN -> SiLU -> GEMM2(128) -> +b -> scatter-add
__global__ __launch_bounds__(256) void edge_mlp(
    const float* __restrict__ hn,
    const int* __restrict__ erow, const int* __restrict__ ecol,
    const float* __restrict__ ea,
    const float* __restrict__ W1, const float* __restrict__ b1,
    const float* __restrict__ lng, const float* __restrict__ lnb,
    const float* __restrict__ W2, const float* __restrict__ b2,
    float* __restrict__ agg)
{
  __shared__ float As[64][36];
  __shared__ float Bs[32][128];
  __shared__ float Ts[64][132];
  __shared__ int idx2[128];  // [0..63]=row, [64..127]=col
  const int tid = threadIdx.x;
  const int tx8 = (tid & 15) * 8;
  const int ty4 = (tid >> 4) * 4;
  const int e0 = blockIdx.x * 64;
  if (tid < 64) { idx2[tid] = erow[e0 + tid]; idx2[64 + tid] = ecol[e0 + tid]; }
  __syncthreads();

  float acc[4][8] = {};
  for (int kc = 0; kc < 9; ++kc) {
    if (kc < 8) {
      const int* idx = idx2 + ((kc < 4) ? 0 : 64);
      const int k0 = (kc & 3) * 32;
      #pragma unroll
      for (int i = 0; i < 2; ++i) {
        int s = tid + i * 256;
        int e = s >> 3, f4 = (s & 7) * 4;
        *(float4*)&As[e][f4] = *(const float4*)(hn + (size_t)idx[e] * HID + k0 + f4);
      }
      int m = tid >> 1, kks = (tid & 1) * 16;
      const float* wr = W1 + (size_t)m * 272 + kc * 32 + kks;
      #pragma unroll
      for (int j = 0; j < 16; ++j) Bs[kks + j][m] = wr[j];
    } else {
      int e = tid >> 2, f4 = (tid & 3) * 4;
      *(float4*)&As[e][f4] = *(const float4*)(ea + (size_t)(e0 + e) * 16 + f4);
      int m = tid >> 1;
      if ((tid & 1) == 0) {
        const float* wr = W1 + (size_t)m * 272 + 256;
        #pragma unroll
        for (int j = 0; j < 16; ++j) Bs[j][m] = wr[j];
      }
    }
    __syncthreads();
    if (kc < 8) gemm_chunk<32>(As, Bs, ty4, tx8, acc);
    else        gemm_chunk<16>(As, Bs, ty4, tx8, acc);
    __syncthreads();
  }

  // bias + LN + SiLU -> Ts
  {
    float bv[8], gv[8], lv[8];
    #pragma unroll
    for (int j = 0; j < 8; ++j) { bv[j] = b1[tx8 + j]; gv[j] = lng[tx8 + j]; lv[j] = lnb[tx8 + j]; }
    #pragma unroll
    for (int i = 0; i < 4; ++i) {
      #pragma unroll
      for (int j = 0; j < 8; ++j) acc[i][j] += bv[j];
      float s1 = 0.f, s2 = 0.f;
      #pragma unroll
      for (int j = 0; j < 8; ++j) { s1 += acc[i][j]; s2 += acc[i][j] * acc[i][j]; }
      #pragma unroll
      for (int m = 1; m < 16; m <<= 1) { s1 += __shfl_xor(s1, m, 64); s2 += __shfl_xor(s2, m, 64); }
      float mu = s1 * (1.0f / 128.0f);
      float var = s2 * (1.0f / 128.0f) - mu * mu;
      float rs = rsqrtf(var + 1e-5f);
      float t[8];
      #pragma unroll
      for (int j = 0; j < 8; ++j) t[j] = silu_f((acc[i][j] - mu) * rs * gv[j] + lv[j]);
      *(float4*)&Ts[ty4 + i][tx8]     = make_float4(t[0], t[1], t[2], t[3]);
      *(float4*)&Ts[ty4 + i][tx8 + 4] = make_float4(t[4], t[5], t[6], t[7]);
    }
  }

  // GEMM2: m = Ts @ W2^T (K=128)
  float acc2[4][8] = {};
  for (int kc = 0; kc < 4; ++kc) {
    int m = tid >> 1, kks = (tid & 1) * 16;
    const float* wr = W2 + (size_t)m * 128 + kc * 32 + kks;
    #pragma unroll
    for (int j = 0; j < 16; ++j) Bs[kks + j][m] = wr[j];
    __syncthreads();
    const int k0 = kc * 32;
    #pragma unroll 8
    for (int kk = 0; kk < 32; ++kk) {
      float a[4];
      #pragma unroll
      for (int i = 0; i < 4; ++i) a[i] = Ts[ty4 + i][k0 + kk];
      const float4 u = *(const float4*)&Bs[kk][tx8];
      const float4 v = *(const float4*)&Bs[kk][tx8 + 4];
      const float bb[8] = {u.x, u.y, u.z, u.w, v.x, v.y, v.z, v.w};
      #pragma unroll
      for (int i = 0; i < 4; ++i)
        #pragma unroll
        for (int j = 0; j < 8; ++j)
          acc2[i][j] = fmaf(a[i], bb[j], acc2[i][j]);
    }
    __syncthreads();
  }

  // bias + scatter-add into agg[row]
  {
    float bv[8];
    #pragma unroll
    for (int j = 0; j < 8; ++j) bv[j] = b2[tx8 + j];
    #pragma unroll
    for (int i = 0; i < 4; ++i) {
      int r = idx2[ty4 + i];
      float* dst = agg + (size_t)r * HID + tx8;
      #pragma unroll
      for (int j = 0; j < 8; ++j) unsafeAtomicAdd(dst + j, acc2[i][j] + bv[j]);
    }
  }
}

extern "C" void kernel_launch(void* const* d_in, const int* in_sizes, int n_in,
                              void* d_out, int out_size, void* d_ws, size_t ws_size,
                              hipStream_t stream)
{
  const float* in_h  = (const float*)d_in[0];
  const int*   edges = (const int*)d_in[1];
  const float* ea    = (const float*)d_in[2];
  const float* ei_w1 = (const float*)d_in[3];
  const float* ei_b1 = (const float*)d_in[4];
  const float* ei_w2 = (const float*)d_in[5];
  const float* ei_b2 = (const float*)d_in[6];
  const float* ng    = (const float*)d_in[7];
  const float* nbp   = (const float*)d_in[8];
  const float* ew1   = (const float*)d_in[9];
  const float* eb1   = (const float*)d_in[10];
  const float* elg   = (const float*)d_in[11];
  const float* elb   = (const float*)d_in[12];
  const float* ew2   = (const float*)d_in[13];
  const float* eb2   = (const float*)d_in[14];
  const float* nw1   = (const float*)d_in[15];
  const float* nb1   = (const float*)d_in[16];
  const float* nlg   = (const float*)d_in[17];
  const float* nlb   = (const float*)d_in[18];
  const float* nw2   = (const float*)d_in[19];
  const float* nb2   = (const float*)d_in[20];
  const float* eo_w1 = (const float*)d_in[21];
  const float* eo_b1 = (const float*)d_in[22];
  const float* eo_w2 = (const float*)d_in[23];
  const float* eo_b2 = (const float*)d_in[24];

  float* h   = (float*)d_ws;
  float* hn  = h   + (size_t)NN * HID;
  float* agg = hn  + (size_t)NN * HID;
  float* tmp = agg + (size_t)NN * HID;

  const int NB  = (NN + 63) / 64;          // 782
  const int EB  = NE / 64;                 // 12500
  const int LNB = (NN + 3) / 4;            // 12500
  const int ZB  = (NN * HID / 4 + 255) / 256;  // 6250

  const int* erow = edges;
  const int* ecol = edges + NE;

  // embedding_in
  node_gemm<128, false, true,  false><<<NB, 256, 0, stream>>>(in_h, nullptr, ei_w1, ei_b1, nullptr, nullptr, nullptr, tmp, NN);
  node_gemm<128, false, false, false><<<NB, 256, 0, stream>>>(tmp,  nullptr, ei_w2, ei_b2, nullptr, nullptr, nullptr, h,   NN);

  for (int l = 0; l < 4; ++l) {
    ln_kernel<<<LNB, 256, 0, stream>>>(h, ng + 128 * l, nbp + 128 * l, hn, NN);
    zero4_kernel<<<ZB, 256, 0, stream>>>((float4*)agg, NN * HID / 4);
    edge_mlp<<<EB, 256, 0, stream>>>(hn, erow, ecol, ea,
        ew1 + 34816 * l, eb1 + 128 * l, elg + 128 * l, elb + 128 * l,
        ew2 + 16384 * l, eb2 + 128 * l, agg);
    node_gemm<256, true,  true,  false><<<NB, 256, 0, stream>>>(hn, agg, nw1 + 32768 * l, nb1 + 128 * l,
        nlg + 128 * l, nlb + 128 * l, nullptr, tmp, NN);
    node_gemm<128, false, false, true ><<<NB, 256, 0, stream>>>(tmp, nullptr, nw2 + 16384 * l, nb2 + 128 * l,
        nullptr, nullptr, hn, h, NN);
  }

  // embedding_out
  node_gemm<128, false, true,  false><<<NB, 256, 0, stream>>>(h,   nullptr, eo_w1, eo_b1, nullptr, nullptr, nullptr, tmp, NN);
  node_gemm<128, false, false, false><<<NB, 256, 0, stream>>>(tmp, nullptr, eo_w2, eo_b2, nullptr, nullptr, nullptr, (float*)d_out, NN);
}

// Round 2
// 2306.156 us; speedup vs baseline: 5.4991x; 5.4991x over previous
//
#include <hip/hip_runtime.h>
#include <math.h>

#define NN 50000
#define NE 800000
#define HID 128
#define NNH ((size_t)NN * HID)

typedef __attribute__((ext_vector_type(8))) short short8;
typedef __attribute__((ext_vector_type(4))) float f32x4;

__device__ __forceinline__ ushort f2bf(float f) {
  unsigned u = __float_as_uint(f);
  unsigned r = (u + 0x7fffu + ((u >> 16) & 1u)) >> 16;
  return (ushort)r;
}
__device__ __forceinline__ float silu_f(float x) { return x / (1.0f + __expf(-x)); }

// ---------------- fp32 LayerNorm over rows of 128 ----------------
__global__ __launch_bounds__(256) void ln_kernel(const float* __restrict__ h,
    const float* __restrict__ g, const float* __restrict__ b,
    float* __restrict__ o, int n)
{
  int r = blockIdx.x * 4 + (threadIdx.x >> 6);
  int lane = threadIdx.x & 63;
  if (r >= n) return;
  const float* hr = h + (size_t)r * HID;
  float v0 = hr[lane], v1 = hr[lane + 64];
  float s1 = v0 + v1, s2 = v0 * v0 + v1 * v1;
  #pragma unroll
  for (int m = 1; m < 64; m <<= 1) {
    s1 += __shfl_xor(s1, m, 64);
    s2 += __shfl_xor(s2, m, 64);
  }
  float mu = s1 * (1.0f / 128.0f);
  float var = s2 * (1.0f / 128.0f) - mu * mu;
  float rs = rsqrtf(var + 1e-5f);
  float* orow = o + (size_t)r * HID;
  orow[lane]      = (v0 - mu) * rs * g[lane]      + b[lane];
  orow[lane + 64] = (v1 - mu) * rs * g[lane + 64] + b[lane + 64];
}

__global__ __launch_bounds__(256) void zero4_kernel(float4* __restrict__ p, int n4)
{
  int i = blockIdx.x * 256 + threadIdx.x;
  if (i < n4) p[i] = make_float4(0.f, 0.f, 0.f, 0.f);
}

// d[r*dcols+c] = c<scols ? bf16(s[r*sstride+soff+c]) : 0
__global__ __launch_bounds__(256) void cvt_slice(const float* __restrict__ s, ushort* __restrict__ d,
    int rows, int sstride, int soff, int scols, int dcols)
{
  int i = blockIdx.x * 256 + threadIdx.x;
  if (i >= rows * dcols) return;
  int r = i / dcols, c = i - r * dcols;
  d[i] = (c < scols) ? f2bf(s[r * sstride + soff + c]) : (ushort)0;
}

// ---------------- MFMA GEMM: C = [R +] act(ln?(A @ W^T + bias)) ----------------
// A = [n][KT] fp32 (KT==256: concat of A0,A1 along cols), W = bf16 [128][KT] row-major.
// Block: 64 rows x 128 cols, 4 waves, wave = 16 rows. mfma_f32_16x16x32_bf16.
template<int KT, bool DOBIAS, bool DOLN, bool DOSILU, bool DORES>
__global__ __launch_bounds__(256) void mgemm(
    const float* __restrict__ A0, const float* __restrict__ A1,
    const ushort* __restrict__ Wbf, const float* __restrict__ bias,
    const float* __restrict__ lng, const float* __restrict__ lnb,
    const float* __restrict__ R, float* __restrict__ C, int n)
{
  constexpr int LDA = (KT == 256) ? 264 : 136;  // ushorts, 16B-aligned rows
  __shared__ ushort Al[64][LDA];
  const int tid = threadIdx.x;
  const int n0 = blockIdx.x * 64;

  constexpr int SPR = KT / 4;              // float4 slots per row
  #pragma unroll
  for (int i = 0; i < (64 * KT / 4) / 256; ++i) {
    int s = tid + i * 256;
    int row = s / SPR;
    int c4 = (s % SPR) * 4;
    int gr = n0 + row;
    float4 v = make_float4(0.f, 0.f, 0.f, 0.f);
    if (gr < n) {
      if (KT == 256)
        v = (c4 < 128) ? *(const float4*)(A0 + (size_t)gr * HID + c4)
                       : *(const float4*)(A1 + (size_t)gr * HID + (c4 - 128));
      else
        v = *(const float4*)(A0 + (size_t)gr * HID + c4);
    }
    uint2 p;
    p.x = (uint)f2bf(v.x) | ((uint)f2bf(v.y) << 16);
    p.y = (uint)f2bf(v.z) | ((uint)f2bf(v.w) << 16);
    *(uint2*)&Al[row][c4] = p;
  }
  __syncthreads();

  const int w = tid >> 6, l = tid & 63;
  const int lr = l & 15, lh = l >> 4;

  f32x4 zf = {0.f, 0.f, 0.f, 0.f};
  f32x4 acc[8];
  #pragma unroll
  for (int nt = 0; nt < 8; ++nt) acc[nt] = zf;

  #pragma unroll
  for (int q = 0; q < KT / 32; ++q) {
    short8 af = *(const short8*)&Al[w * 16 + lr][q * 32 + lh * 8];
    #pragma unroll
    for (int nt = 0; nt < 8; ++nt) {
      short8 bf = *(const short8*)(Wbf + (size_t)(nt * 16 + lr) * KT + q * 32 + lh * 8);
      acc[nt] = __builtin_amdgcn_mfma_f32_16x16x32_bf16(af, bf, acc[nt], 0, 0, 0);
    }
  }

  float vb[8], gv[8], bv[8];
  #pragma unroll
  for (int nt = 0; nt < 8; ++nt) {
    int col = nt * 16 + lr;
    vb[nt] = DOBIAS ? bias[col] : 0.f;
    if (DOLN) { gv[nt] = lng[col]; bv[nt] = lnb[col]; }
  }

  #pragma unroll
  for (int r = 0; r < 4; ++r) {
    float vals[8];
    #pragma unroll
    for (int nt = 0; nt < 8; ++nt) vals[nt] = acc[nt][r] + vb[nt];
    if (DOLN) {
      float s1 = 0.f, s2 = 0.f;
      #pragma unroll
      for (int nt = 0; nt < 8; ++nt) { s1 += vals[nt]; s2 += vals[nt] * vals[nt]; }
      #pragma unroll
      for (int m = 1; m < 16; m <<= 1) { s1 += __shfl_xor(s1, m, 64); s2 += __shfl_xor(s2, m, 64); }
      float mu = s1 * (1.0f / 128.0f);
      float var = s2 * (1.0f / 128.0f) - mu * mu;
      float rs = rsqrtf(var + 1e-5f);
      #pragma unroll
      for (int nt = 0; nt < 8; ++nt) vals[nt] = (vals[nt] - mu) * rs * gv[nt] + bv[nt];
    }
    if (DOSILU) {
      #pragma unroll
      for (int nt = 0; nt < 8; ++nt) vals[nt] = silu_f(vals[nt]);
    }
    int row = n0 + w * 16 + lh * 4 + r;
    if (row < n) {
      float* cr = C + (size_t)row * HID;
      #pragma unroll
      for (int nt = 0; nt < 8; ++nt) {
        int col = nt * 16 + lr;
        float o = vals[nt];
        if (DORES) o += R[(size_t)row * HID + col];
        cr[col] = o;
      }
    }
  }
}

// ---------------- Fused edge kernel ----------------
// Per block: 64 edges, 4 waves, wave = 16 edges.
// m1 = Pa[src] + Pb[dst] + ea@W1c^T (K=16 MFMA, zero-padded to 32)  [b1 folded into Pa]
// -> LN -> SiLU -> (bf16, LDS transpose) -> @W2^T (K=128 MFMA) -> +b2 -> atomic scatter to agg[src]
__global__ __launch_bounds__(256) void edge_fused(
    const float* __restrict__ Pa, const float* __restrict__ Pb,
    const float* __restrict__ ea,
    const int* __restrict__ esrc, const int* __restrict__ edst,
    const ushort* __restrict__ W1c,           // [128][32] bf16, k>=16 zero
    const float* __restrict__ elg, const float* __restrict__ elb,
    const ushort* __restrict__ W2bf,          // [128][128] bf16
    const float* __restrict__ b2,
    float* __restrict__ agg)
{
  __shared__ ushort Ts[4][16][136];           // per-wave 16x128 bf16, 16B-aligned rows
  const int tid = threadIdx.x;
  const int w = tid >> 6, l = tid & 63;
  const int lr = l & 15, lh = l >> 4;
  const int e0 = blockIdx.x * 64 + w * 16;

  // phase-1 A-frag from edge_attr (k 0..15 real, 16..31 zero)
  short8 af = {0, 0, 0, 0, 0, 0, 0, 0};
  if (lh < 2) {
    const float* p = ea + (size_t)(e0 + lr) * 16 + lh * 8;
    float4 u = *(const float4*)p, v = *(const float4*)(p + 4);
    af[0] = (short)f2bf(u.x); af[1] = (short)f2bf(u.y);
    af[2] = (short)f2bf(u.z); af[3] = (short)f2bf(u.w);
    af[4] = (short)f2bf(v.x); af[5] = (short)f2bf(v.y);
    af[6] = (short)f2bf(v.z); af[7] = (short)f2bf(v.w);
  }

  f32x4 zf = {0.f, 0.f, 0.f, 0.f};
  f32x4 acc[8];
  #pragma unroll
  for (int nt = 0; nt < 8; ++nt) acc[nt] = zf;
  #pragma unroll
  for (int nt = 0; nt < 8; ++nt) {
    short8 bf = *(const short8*)(W1c + (nt * 16 + lr) * 32 + lh * 8);
    acc[nt] = __builtin_amdgcn_mfma_f32_16x16x32_bf16(af, bf, acc[nt], 0, 0, 0);
  }

  int sr[4], dr[4];
  #pragma unroll
  for (int r = 0; r < 4; ++r) {
    int e = e0 + lh * 4 + r;
    sr[r] = esrc[e]; dr[r] = edst[e];
  }

  // fp32 gather-adds of the node-precomputed GEMM1 halves
  #pragma unroll
  for (int nt = 0; nt < 8; ++nt) {
    int col = nt * 16 + lr;
    #pragma unroll
    for (int r = 0; r < 4; ++r)
      acc[nt][r] += Pa[(size_t)sr[r] * HID + col] + Pb[(size_t)dr[r] * HID + col];
  }

  float gv[8], bv[8];
  #pragma unroll
  for (int nt = 0; nt < 8; ++nt) { gv[nt] = elg[nt * 16 + lr]; bv[nt] = elb[nt * 16 + lr]; }

  // LN + SiLU in C/D layout, write bf16 transpose tile
  #pragma unroll
  for (int r = 0; r < 4; ++r) {
    float vals[8];
    #pragma unroll
    for (int nt = 0; nt < 8; ++nt) vals[nt] = acc[nt][r];
    float s1 = 0.f, s2 = 0.f;
    #pragma unroll
    for (int nt = 0; nt < 8; ++nt) { s1 += vals[nt]; s2 += vals[nt] * vals[nt]; }
    #pragma unroll
    for (int m = 1; m < 16; m <<= 1) { s1 += __shfl_xor(s1, m, 64); s2 += __shfl_xor(s2, m, 64); }
    float mu = s1 * (1.0f / 128.0f);
    float var = s2 * (1.0f / 128.0f) - mu * mu;
    float rs = rsqrtf(var + 1e-5f);
    #pragma unroll
    for (int nt = 0; nt < 8; ++nt) {
      float t = silu_f((vals[nt] - mu) * rs * gv[nt] + bv[nt]);
      Ts[w][lh * 4 + r][nt * 16 + lr] = f2bf(t);
    }
  }
  // per-wave private Ts: wave-internal lgkmcnt ordering suffices, no __syncthreads

  // phase-2: m = T @ W2^T, K=128
  f32x4 acc2[8];
  #pragma unroll
  for (int nt = 0; nt < 8; ++nt) acc2[nt] = zf;
  #pragma unroll
  for (int q = 0; q < 4; ++q) {
    short8 a2 = *(const short8*)&Ts[w][lr][q * 32 + lh * 8];
    #pragma unroll
    for (int nt = 0; nt < 8; ++nt) {
      short8 bf = *(const short8*)(W2bf + (size_t)(nt * 16 + lr) * HID + q * 32 + lh * 8);
      acc2[nt] = __builtin_amdgcn_mfma_f32_16x16x32_bf16(a2, bf, acc2[nt], 0, 0, 0);
    }
  }

  #pragma unroll
  for (int nt = 0; nt < 8; ++nt) {
    int col = nt * 16 + lr;
    float bb = b2[col];
    #pragma unroll
    for (int r = 0; r < 4; ++r)
      unsafeAtomicAdd(agg + (size_t)sr[r] * HID + col, acc2[nt][r] + bb);
  }
}

extern "C" void kernel_launch(void* const* d_in, const int* in_sizes, int n_in,
                              void* d_out, int out_size, void* d_ws, size_t ws_size,
                              hipStream_t stream)
{
  const float* in_h  = (const float*)d_in[0];
  const int*   edges = (const int*)d_in[1];
  const float* ea    = (const float*)d_in[2];
  const float* ei_w1 = (const float*)d_in[3];
  const float* ei_b1 = (const float*)d_in[4];
  const float* ei_w2 = (const float*)d_in[5];
  const float* ei_b2 = (const float*)d_in[6];
  const float* ng    = (const float*)d_in[7];
  const float* nbp   = (const float*)d_in[8];
  const float* ew1   = (const float*)d_in[9];
  const float* eb1   = (const float*)d_in[10];
  const float* elg   = (const float*)d_in[11];
  const float* elb   = (const float*)d_in[12];
  const float* ew2   = (const float*)d_in[13];
  const float* eb2   = (const float*)d_in[14];
  const float* nw1   = (const float*)d_in[15];
  const float* nb1   = (const float*)d_in[16];
  const float* nlg   = (const float*)d_in[17];
  const float* nlb   = (const float*)d_in[18];
  const float* nw2   = (const float*)d_in[19];
  const float* nb2   = (const float*)d_in[20];
  const float* eo_w1 = (const float*)d_in[21];
  const float* eo_b1 = (const float*)d_in[22];
  const float* eo_w2 = (const float*)d_in[23];
  const float* eo_b2 = (const float*)d_in[24];

  float* wf    = (float*)d_ws;
  float* B_h   = wf;
  float* B_hn  = wf + NNH;
  float* B_agg = wf + 2 * NNH;
  float* B_tmp = wf + 3 * NNH;   // also Pa, also node-MLP intermediate
  float* B_pb  = wf + 4 * NNH;
  ushort* wu   = (ushort*)(wf + 5 * NNH);
  ushort* w_ei1 = wu;
  ushort* w_ei2 = wu + 16384;
  ushort* w_eo1 = wu + 32768;
  ushort* w_eo2 = wu + 49152;
  // per-layer: base = wu + 65536 + l*102400:
  //   +0 Wa | +16384 Wb | +32768 W2 | +49152 N1 | +81920 N2 | +98304 W1c[128][32]

  const int NB  = (NN + 63) / 64;              // 782
  const int EB  = NE / 64;                     // 12500
  const int LNB = (NN + 3) / 4;                // 12500
  const int ZB  = ((int)(NNH / 4) + 255) / 256; // 6250

  const int* erow = edges;
  const int* ecol = edges + NE;

  auto CVT = [&](const float* s, ushort* d, int rows, int sstride, int soff, int scols, int dcols) {
    int n = rows * dcols;
    cvt_slice<<<(n + 255) / 256, 256, 0, stream>>>(s, d, rows, sstride, soff, scols, dcols);
  };

  // weight prep (bf16), every launch (deterministic)
  CVT(ei_w1, w_ei1, 128, 128, 0, 128, 128);
  CVT(ei_w2, w_ei2, 128, 128, 0, 128, 128);
  CVT(eo_w1, w_eo1, 128, 128, 0, 128, 128);
  CVT(eo_w2, w_eo2, 128, 128, 0, 128, 128);
  for (int lyr = 0; lyr < 4; ++lyr) {
    ushort* base = wu + 65536 + lyr * 102400;
    CVT(ew1 + 34816 * lyr, base + 0,     128, 272, 0,   128, 128);  // Wa
    CVT(ew1 + 34816 * lyr, base + 16384, 128, 272, 128, 128, 128);  // Wb
    CVT(ew2 + 16384 * lyr, base + 32768, 128, 128, 0,   128, 128);  // W2
    CVT(nw1 + 32768 * lyr, base + 49152, 128, 256, 0,   256, 256);  // N1
    CVT(nw2 + 16384 * lyr, base + 81920, 128, 128, 0,   128, 128);  // N2
    CVT(ew1 + 34816 * lyr, base + 98304, 128, 272, 256, 16,  32);   // W1c zero-padded
  }

  // embedding_in
  mgemm<128, true, false, true,  false><<<NB, 256, 0, stream>>>(in_h, nullptr, w_ei1, ei_b1, nullptr, nullptr, nullptr, B_tmp, NN);
  mgemm<128, true, false, false, false><<<NB, 256, 0, stream>>>(B_tmp, nullptr, w_ei2, ei_b2, nullptr, nullptr, nullptr, B_h, NN);

  for (int lyr = 0; lyr < 4; ++lyr) {
    ushort* base = wu + 65536 + lyr * 102400;
    ln_kernel<<<LNB, 256, 0, stream>>>(B_h, ng + 128 * lyr, nbp + 128 * lyr, B_hn, NN);
    // Pa = hn@Wa^T + b1 ; Pb = hn@Wb^T
    mgemm<128, true,  false, false, false><<<NB, 256, 0, stream>>>(B_hn, nullptr, base + 0,     eb1 + 128 * lyr, nullptr, nullptr, nullptr, B_tmp, NN);
    mgemm<128, false, false, false, false><<<NB, 256, 0, stream>>>(B_hn, nullptr, base + 16384, nullptr,         nullptr, nullptr, nullptr, B_pb,  NN);
    zero4_kernel<<<ZB, 256, 0, stream>>>((float4*)B_agg, (int)(NNH / 4));
    edge_fused<<<EB, 256, 0, stream>>>(B_tmp, B_pb, ea, erow, ecol,
        base + 98304, elg + 128 * lyr, elb + 128 * lyr, base + 32768, eb2 + 128 * lyr, B_agg);
    // node MLP
    mgemm<256, true, true,  true,  false><<<NB, 256, 0, stream>>>(B_hn, B_agg, base + 49152, nb1 + 128 * lyr,
        nlg + 128 * lyr, nlb + 128 * lyr, nullptr, B_tmp, NN);
    mgemm<128, true, false, false, true ><<<NB, 256, 0, stream>>>(B_tmp, nullptr, base + 81920, nb2 + 128 * lyr,
        nullptr, nullptr, B_hn, B_h, NN);
  }

  // embedding_out
  mgemm<128, true, false, true,  false><<<NB, 256, 0, stream>>>(B_h, nullptr, w_eo1, eo_b1, nullptr, nullptr, nullptr, B_tmp, NN);
  mgemm<128, true, false, false, false><<<NB, 256, 0, stream>>>(B_tmp, nullptr, w_eo2, eo_b2, nullptr, nullptr, nullptr, (float*)d_out, NN);
}